// Round 1
// baseline (365.731 us; speedup 1.0000x reference)
//
#include <hip/hip_runtime.h>

#define N_SITES 100000
#define C_IN 256
#define C_MID 64
#define C_OUT 256

typedef __attribute__((ext_vector_type(8))) short bf16x8;   // 8 bf16 in 4 VGPRs
typedef __attribute__((ext_vector_type(4))) float f32x4;    // MFMA C/D frag

__device__ inline short f2bf(float f) {
  // round-to-nearest-even f32 -> bf16
  unsigned u = __builtin_bit_cast(unsigned, f);
  u += 0x7fffu + ((u >> 16) & 1u);
  return (short)(u >> 16);
}

__device__ inline f32x4 mfma16(bf16x8 a, bf16x8 b, f32x4 c) {
  return __builtin_amdgcn_mfma_f32_16x16x32_bf16(a, b, c, 0, 0, 0);
}

// ---------------------------------------------------------------------------
// Prep: W1T[n][k] = W1[k][n] (bf16), W2T[k][dout][din] = W2[k][din][dout],
//       W3T[n][k] = W3[k][n], zero h1 pad row (row N_SITES).
// Re-run every launch: d_ws is re-poisoned before each timed call.
// ---------------------------------------------------------------------------
__global__ __launch_bounds__(256) void k_prep(const float* __restrict__ W1,
                                              const float* __restrict__ W2,
                                              const float* __restrict__ W3,
                                              short* __restrict__ W1T,
                                              short* __restrict__ W2T,
                                              short* __restrict__ W3T,
                                              short* __restrict__ h1) {
  int i = blockIdx.x * 256 + threadIdx.x;
  if (i < 16384) {                       // W1T: [64][256]
    int n = i >> 8, k = i & 255;
    W1T[i] = f2bf(W1[k * 64 + n]);
  } else if (i < 16384 + 110592) {       // W2T: [27][64][64]
    int j = i - 16384;
    int k = j >> 12, rem = j & 4095;
    int dout = rem >> 6, din = rem & 63;
    W2T[j] = f2bf(W2[k * 4096 + din * 64 + dout]);
  } else if (i < 16384 + 110592 + 16384) {  // W3T: [256][64]
    int j = i - (16384 + 110592);
    int n = j >> 6, k = j & 63;
    W3T[j] = f2bf(W3[k * 256 + n]);
  } else if (i < 16384 + 110592 + 16384 + 64) {  // h1 pad row
    h1[(size_t)N_SITES * 64 + (i - (16384 + 110592 + 16384))] = 0;
  }
}

// ---------------------------------------------------------------------------
// conv1: h1[n][c] = relu(g1[c] * (F @ W1)[n][c] + b1[c]), bf16 out.
// Block = 4 waves, each wave: 16 rows x 64 cols, K=256 in 8 steps of 32.
// ---------------------------------------------------------------------------
__global__ __launch_bounds__(256) void k_conv1(const float* __restrict__ F,
                                               const short* __restrict__ W1T,
                                               const float* __restrict__ g1,
                                               const float* __restrict__ b1,
                                               short* __restrict__ h1) {
  int tid = threadIdx.x;
  int lane = tid & 63, wave = tid >> 6;
  int l15 = lane & 15, l4 = lane >> 4;
  int base = blockIdx.x * 64 + wave * 16;

  int row = base + l15;
  int rowc = row < N_SITES ? row : (N_SITES - 1);
  const float* fr = F + (size_t)rowc * 256 + l4 * 8;

  f32x4 acc[4];
#pragma unroll
  for (int nf = 0; nf < 4; ++nf) acc[nf] = (f32x4){0.f, 0.f, 0.f, 0.f};

#pragma unroll
  for (int kk = 0; kk < 8; ++kk) {
    float4 a0 = *(const float4*)(fr + kk * 32);
    float4 a1 = *(const float4*)(fr + kk * 32 + 4);
    bf16x8 af;
    af[0] = f2bf(a0.x); af[1] = f2bf(a0.y); af[2] = f2bf(a0.z); af[3] = f2bf(a0.w);
    af[4] = f2bf(a1.x); af[5] = f2bf(a1.y); af[6] = f2bf(a1.z); af[7] = f2bf(a1.w);
#pragma unroll
    for (int nf = 0; nf < 4; ++nf) {
      bf16x8 bf = *(const bf16x8*)(W1T + (nf * 16 + l15) * 256 + kk * 32 + l4 * 8);
      acc[nf] = mfma16(af, bf, acc[nf]);
    }
  }

#pragma unroll
  for (int nf = 0; nf < 4; ++nf) {
    int col = nf * 16 + l15;
    float g = g1[col], bb = b1[col];
#pragma unroll
    for (int r = 0; r < 4; ++r) {
      int site = base + l4 * 4 + r;   // D row = (lane>>4)*4 + reg
      if (site < N_SITES) {
        float v = fmaxf(acc[nf][r] * g + bb, 0.f);
        h1[(size_t)site * 64 + col] = f2bf(v);
      }
    }
  }
}

// ---------------------------------------------------------------------------
// conv2: gather-GEMM over 27 neighbors. h2[n][d] =
//   relu(g2[d] * sum_k sum_c h1[nb[n][k]][c] * W2[k][c][d] + b2[d]).
// Block = 4 waves x 32 rows = 128 rows. nb tile in LDS.
// Missing neighbors (idx == N_SITES) hit the zeroed pad row of h1.
// ---------------------------------------------------------------------------
__global__ __launch_bounds__(256) void k_conv2(const short* __restrict__ h1,
                                               const short* __restrict__ W2T,
                                               const float* __restrict__ g2,
                                               const float* __restrict__ b2,
                                               const int* __restrict__ NB,
                                               short* __restrict__ h2) {
  __shared__ int nbt[128 * 27];
  int tid = threadIdx.x;
  int blockbase = blockIdx.x * 128;
  for (int i = tid; i < 128 * 27; i += 256) {
    int site = blockbase + i / 27;
    nbt[i] = (site < N_SITES) ? NB[(size_t)site * 27 + (i % 27)] : N_SITES;
  }
  __syncthreads();

  int lane = tid & 63, wave = tid >> 6;
  int l15 = lane & 15, l4 = lane >> 4;
  int rowl0 = wave * 32 + l15;
  int rowl1 = wave * 32 + 16 + l15;

  f32x4 acc[2][4];
#pragma unroll
  for (int mf = 0; mf < 2; ++mf)
#pragma unroll
    for (int nf = 0; nf < 4; ++nf) acc[mf][nf] = (f32x4){0.f, 0.f, 0.f, 0.f};

  for (int k = 0; k < 27; ++k) {
    int n0 = nbt[rowl0 * 27 + k];
    int n1 = nbt[rowl1 * 27 + k];
    const short* p0 = h1 + (size_t)n0 * 64 + l4 * 8;
    const short* p1 = h1 + (size_t)n1 * 64 + l4 * 8;
#pragma unroll
    for (int kkk = 0; kkk < 2; ++kkk) {
      bf16x8 a0 = *(const bf16x8*)(p0 + kkk * 32);
      bf16x8 a1 = *(const bf16x8*)(p1 + kkk * 32);
#pragma unroll
      for (int nf = 0; nf < 4; ++nf) {
        bf16x8 bfr = *(const bf16x8*)(W2T + (k * 64 + nf * 16 + l15) * 64 + kkk * 32 + l4 * 8);
        acc[0][nf] = mfma16(a0, bfr, acc[0][nf]);
        acc[1][nf] = mfma16(a1, bfr, acc[1][nf]);
      }
    }
  }

#pragma unroll
  for (int mf = 0; mf < 2; ++mf) {
#pragma unroll
    for (int nf = 0; nf < 4; ++nf) {
      int col = nf * 16 + l15;
      float g = g2[col], bb = b2[col];
#pragma unroll
      for (int r = 0; r < 4; ++r) {
        int site = blockbase + wave * 32 + mf * 16 + l4 * 4 + r;
        if (site < N_SITES) {
          float v = fmaxf(acc[mf][nf][r] * g + bb, 0.f);
          h2[(size_t)site * 64 + col] = f2bf(v);
        }
      }
    }
  }
}

// ---------------------------------------------------------------------------
// conv3 + affine + residual + relu, fp32 out.
// Block = 32 rows x 256 cols; wave w covers cols [w*64, w*64+64). K=64.
// 100000 % 32 == 0, so no bounds checks.
// ---------------------------------------------------------------------------
__global__ __launch_bounds__(256) void k_conv3(const short* __restrict__ h2,
                                               const short* __restrict__ W3T,
                                               const float* __restrict__ g3,
                                               const float* __restrict__ b3,
                                               const float* __restrict__ F,
                                               float* __restrict__ out) {
  int tid = threadIdx.x;
  int lane = tid & 63, wave = tid >> 6;
  int l15 = lane & 15, l4 = lane >> 4;
  int base = blockIdx.x * 32;

  const short* pa0 = h2 + (size_t)(base + l15) * 64 + l4 * 8;
  const short* pa1 = h2 + (size_t)(base + 16 + l15) * 64 + l4 * 8;

  f32x4 acc[2][4];
#pragma unroll
  for (int mf = 0; mf < 2; ++mf)
#pragma unroll
    for (int nf = 0; nf < 4; ++nf) acc[mf][nf] = (f32x4){0.f, 0.f, 0.f, 0.f};

#pragma unroll
  for (int kkk = 0; kkk < 2; ++kkk) {
    bf16x8 a0 = *(const bf16x8*)(pa0 + kkk * 32);
    bf16x8 a1 = *(const bf16x8*)(pa1 + kkk * 32);
#pragma unroll
    for (int nf = 0; nf < 4; ++nf) {
      bf16x8 b = *(const bf16x8*)(W3T + (wave * 64 + nf * 16 + l15) * 64 + kkk * 32 + l4 * 8);
      acc[0][nf] = mfma16(a0, b, acc[0][nf]);
      acc[1][nf] = mfma16(a1, b, acc[1][nf]);
    }
  }

#pragma unroll
  for (int mf = 0; mf < 2; ++mf) {
#pragma unroll
    for (int nf = 0; nf < 4; ++nf) {
      int col = wave * 64 + nf * 16 + l15;
      float g = g3[col], bb = b3[col];
#pragma unroll
      for (int r = 0; r < 4; ++r) {
        int site = base + mf * 16 + l4 * 4 + r;
        size_t o = (size_t)site * 256 + col;
        float v = acc[mf][nf][r] * g + bb + F[o];
        out[o] = fmaxf(v, 0.f);
      }
    }
  }
}

// ---------------------------------------------------------------------------
extern "C" void kernel_launch(void* const* d_in, const int* in_sizes, int n_in,
                              void* d_out, int out_size, void* d_ws, size_t ws_size,
                              hipStream_t stream) {
  const float* F  = (const float*)d_in[0];
  const float* W1 = (const float*)d_in[1];
  const float* W2 = (const float*)d_in[2];
  const float* W3 = (const float*)d_in[3];
  const float* g1 = (const float*)d_in[4];
  const float* b1 = (const float*)d_in[5];
  const float* g2 = (const float*)d_in[6];
  const float* b2 = (const float*)d_in[7];
  const float* g3 = (const float*)d_in[8];
  const float* b3 = (const float*)d_in[9];
  const int*   NB = (const int*)d_in[10];
  float* out = (float*)d_out;

  char* ws = (char*)d_ws;
  short* W1T = (short*)(ws);                                   // 32768 B
  short* W2T = (short*)(ws + 32768);                           // 221184 B
  short* W3T = (short*)(ws + 32768 + 221184);                  // 32768 B
  short* h1  = (short*)(ws + 32768 + 221184 + 32768);          // (N+1)*64*2 = 12800128 B
  short* h2  = (short*)(ws + 32768 + 221184 + 32768 + 12800128); // N*64*2 B

  k_prep<<<dim3(561), dim3(256), 0, stream>>>(W1, W2, W3, W1T, W2T, W3T, h1);
  k_conv1<<<dim3((N_SITES + 63) / 64), dim3(256), 0, stream>>>(F, W1T, g1, b1, h1);
  k_conv2<<<dim3((N_SITES + 127) / 128), dim3(256), 0, stream>>>(h1, W2T, g2, b2, NB, h2);
  k_conv3<<<dim3(N_SITES / 32), dim3(256), 0, stream>>>(h2, W3T, g3, b3, F, out);
}